// Round 13
// baseline (1254.825 us; speedup 1.0000x reference)
//
#include <hip/hip_runtime.h>
#include <hip/hip_bf16.h>
#include <stdint.h>

typedef __bf16 bf16_t;
typedef __bf16 bf16x8_t __attribute__((ext_vector_type(8)));
typedef __bf16 bf16x4_t __attribute__((ext_vector_type(4)));
typedef float  f32x4_t  __attribute__((ext_vector_type(4)));

// ---------------- setup / elementwise kernels ----------------

// dst[c][dst_col0 + k] = src[k][src_col0 + c], k<R, c<C  (transpose + f32->bf16)
__global__ void k_tconv(const float* __restrict__ src, int src_ld, int src_col0, int R, int C,
                        bf16_t* __restrict__ dst, int dst_ld, int dst_col0) {
  __shared__ float t[32][33];
  int c0 = blockIdx.x * 32, k0 = blockIdx.y * 32;
  int tx = threadIdx.x, ty = threadIdx.y;
#pragma unroll
  for (int j = 0; j < 32; j += 8) {
    int k = k0 + ty + j, c = c0 + tx;
    t[ty + j][tx] = src[(long)k * src_ld + src_col0 + c];
  }
  __syncthreads();
#pragma unroll
  for (int j = 0; j < 32; j += 8) {
    int c = c0 + ty + j, k = k0 + tx;
    dst[(long)c * dst_ld + dst_col0 + k] = (bf16_t)t[tx][ty + j];
  }
}

__global__ void k_brz(const float* __restrict__ bih, const float* __restrict__ bhh,
                      float* __restrict__ brz) {
  int c = blockIdx.x * 256 + threadIdx.x;
  if (c < 1024) brz[c] = bih[c] + bhh[c];
}

__global__ void k_scan_rel(const int* __restrict__ rel, int B, int* __restrict__ cum) {
  __shared__ int s[1024];
  int t = threadIdx.x;
  s[t] = (t < B) ? rel[t] : 0;
  __syncthreads();
  for (int off = 1; off < 1024; off <<= 1) {
    int v = (t >= off) ? s[t - off] : 0;
    __syncthreads();
    s[t] += v;
    __syncthreads();
  }
  if (t == 0) cum[0] = 0;
  cum[t + 1] = s[t];
}

__global__ void k_build_src(const int* __restrict__ cum, int B, int Np,
                            int* __restrict__ src, int* __restrict__ pair_pos) {
  int i = blockIdx.x, t = threadIdx.x;
  int c = cum[i], c1 = cum[i + 1];
  int r = c1 - c;
  if (t < r) { int g = c + i + t; src[g] = c + t; pair_pos[c + t] = g; }
  if (t == r) src[c1 + i] = Np + i;
}

__global__ void k_zero_i32(int* __restrict__ p, int n) {
  int i = blockIdx.x * 256 + threadIdx.x;
  if (i < n) p[i] = 0;
}

__global__ void k_count(const int* __restrict__ dvec, int E, int* __restrict__ counts) {
  int e = blockIdx.x * 256 + threadIdx.x;
  if (e < E) atomicAdd(&counts[dvec[e]], 1);
}

__global__ void k_scan_counts(const int* __restrict__ counts, int N,
                              int* __restrict__ row_ptr, int* __restrict__ cursor, int CH) {
  __shared__ int s[1024];
  int t = threadIdx.x;
  int base = t * CH;
  int tot = 0;
  for (int j = 0; j < CH; ++j) { int idx = base + j; if (idx < N) tot += counts[idx]; }
  s[t] = tot;
  __syncthreads();
  for (int off = 1; off < 1024; off <<= 1) {
    int v = (t >= off) ? s[t - off] : 0;
    __syncthreads();
    s[t] += v;
    __syncthreads();
  }
  int excl = s[t] - tot;
  int run = excl;
  for (int j = 0; j < CH; ++j) {
    int idx = base + j;
    if (idx < N) { row_ptr[idx] = run; cursor[idx] = run; run += counts[idx]; }
  }
  if (t == 1023) row_ptr[N] = s[1023];
}

__global__ void k_scatter(const int* __restrict__ svec, const int* __restrict__ dvec, int E,
                          int* __restrict__ cursor, int* __restrict__ esrc) {
  int e = blockIdx.x * 256 + threadIdx.x;
  if (e < E) { int pos = atomicAdd(&cursor[dvec[e]], 1); esrc[pos] = svec[e]; }
}

// Build x (cols 512:1024 of XA). Pair rows from f32 personPair output; person rows from fc_person.
__global__ void k_gather_x(const int* __restrict__ src, const float* __restrict__ PPf,
                           const bf16_t* __restrict__ FCP, int Np, int N,
                           bf16_t* __restrict__ Xcat) {
  long idx = (long)blockIdx.x * 256 + threadIdx.x;
  long g = idx >> 6;
  int t = idx & 63;
  if (g >= N) return;
  int s = src[g];
  bf16x8_t o;
  if (s < Np) {
    const f32x4_t* r4 = reinterpret_cast<const f32x4_t*>(PPf + (long)s * 512);
    f32x4_t a = r4[2 * t], b = r4[2 * t + 1];
    o[0] = (bf16_t)a[0]; o[1] = (bf16_t)a[1]; o[2] = (bf16_t)a[2]; o[3] = (bf16_t)a[3];
    o[4] = (bf16_t)b[0]; o[5] = (bf16_t)b[1]; o[6] = (bf16_t)b[2]; o[7] = (bf16_t)b[3];
  } else {
    o = reinterpret_cast<const bf16x8_t*>(FCP + (long)(s - Np) * 512)[t];
  }
  reinterpret_cast<bf16x8_t*>(Xcat + g * 1024 + 512)[t] = o;
}

// agg[v] = sum over incoming edges of m[src_e]; wave-per-node, bf16x8 per lane
// (64 lanes x 16B = full 1KB row per edge, coalesced). 4 waves/block.
__global__ void k_agg(const bf16_t* __restrict__ m, const int* __restrict__ row_ptr,
                      const int* __restrict__ esrc, bf16_t* __restrict__ Xout, int N) {
  int v = blockIdx.x * 4 + (threadIdx.x >> 6);
  int lane = threadIdx.x & 63;
  if (v >= N) return;
  int beg = row_ptr[v], end = row_ptr[v + 1];
  float a[8] = {0.f, 0.f, 0.f, 0.f, 0.f, 0.f, 0.f, 0.f};
  for (int e = beg; e < end; ++e) {
    int s = esrc[e];
    bf16x8_t mv = reinterpret_cast<const bf16x8_t*>(m + (long)s * 512)[lane];
#pragma unroll
    for (int j = 0; j < 8; ++j) a[j] += (float)mv[j];
  }
  bf16x8_t o;
#pragma unroll
  for (int j = 0; j < 8; ++j) o[j] = (bf16_t)a[j];
  reinterpret_cast<bf16x8_t*>(Xout + (long)v * 1024)[lane] = o;
}

// hLevelF = relu(bbox @ W_bbox + b_bbox), K=8 -> f32 output
__global__ void k_hlevel(const float* __restrict__ bbox, const float* __restrict__ W,
                         const float* __restrict__ b, float* __restrict__ out, int Np) {
  __shared__ float Ws[8][512];
  __shared__ float bs[512];
  int t = threadIdx.x;
  for (int i = t; i < 8 * 512; i += 256) Ws[i >> 9][i & 511] = W[i];
  for (int i = t; i < 512; i += 256) bs[i] = b[i];
  __syncthreads();
  long idx = (long)blockIdx.x * 256 + t;
  long p = idx >> 7;
  int c4 = (int)(idx & 127) * 4;
  if (p >= Np) return;
  f32x4_t bb0 = reinterpret_cast<const f32x4_t*>(bbox + p * 8)[0];
  f32x4_t bb1 = reinterpret_cast<const f32x4_t*>(bbox + p * 8)[1];
  float acc0 = bs[c4], acc1 = bs[c4 + 1], acc2 = bs[c4 + 2], acc3 = bs[c4 + 3];
#pragma unroll
  for (int i = 0; i < 4; ++i) {
    acc0 += bb0[i] * Ws[i][c4];     acc1 += bb0[i] * Ws[i][c4 + 1];
    acc2 += bb0[i] * Ws[i][c4 + 2]; acc3 += bb0[i] * Ws[i][c4 + 3];
    acc0 += bb1[i] * Ws[4 + i][c4];     acc1 += bb1[i] * Ws[4 + i][c4 + 1];
    acc2 += bb1[i] * Ws[4 + i][c4 + 2]; acc3 += bb1[i] * Ws[4 + i][c4 + 3];
  }
  f32x4_t o;
  o[0] = fmaxf(acc0, 0.f); o[1] = fmaxf(acc1, 0.f);
  o[2] = fmaxf(acc2, 0.f); o[3] = fmaxf(acc3, 0.f);
  reinterpret_cast<f32x4_t*>(out + p * 512)[idx & 127] = o;
}

__global__ void k_final(const int* __restrict__ pair_pos, const bf16_t* __restrict__ Xcat,
                        float* __restrict__ outRF, int Np) {
  long idx = (long)blockIdx.x * 256 + threadIdx.x;
  long p = idx >> 6;
  int t = idx & 63;
  if (p >= Np) return;
  int g = pair_pos[p];
  bf16x8_t x = reinterpret_cast<const bf16x8_t*>(Xcat + (long)g * 1024 + 512)[t];
  f32x4_t o0, o1;
#pragma unroll
  for (int j = 0; j < 4; ++j) {
    o0[j] = 1.f / (1.f + __expf(-(float)x[j]));
    o1[j] = 1.f / (1.f + __expf(-(float)x[4 + j]));
  }
  f32x4_t* dst = reinterpret_cast<f32x4_t*>(outRF + p * 512);
  dst[2 * t] = o0;
  dst[2 * t + 1] = o1;
}

// fc_pairClass = RF @ W_cls + b_cls  (K=512, N=6): one wave per row, f32 in/out
__global__ void k_cls(const float* __restrict__ RF, const float* __restrict__ Wc,
                      const float* __restrict__ bc, float* __restrict__ out, int Np) {
  __shared__ float Ws[512 * 6];
  int t = threadIdx.x;
  for (int i = t; i < 512 * 6; i += 256) Ws[i] = Wc[i];
  __syncthreads();
  int wid = t >> 6, lane = t & 63;
  long p = (long)blockIdx.x * 4 + wid;
  if (p >= Np) return;
  const f32x4_t* r4 = reinterpret_cast<const f32x4_t*>(RF + p * 512);
  f32x4_t v0 = r4[2 * lane], v1 = r4[2 * lane + 1];
  float a0 = 0, a1 = 0, a2 = 0, a3 = 0, a4 = 0, a5 = 0;
#pragma unroll
  for (int jj = 0; jj < 8; ++jj) {
    float x = (jj < 4) ? v0[jj] : v1[jj - 4];
    int col = lane * 8 + jj;
    a0 += x * Ws[col * 6 + 0]; a1 += x * Ws[col * 6 + 1]; a2 += x * Ws[col * 6 + 2];
    a3 += x * Ws[col * 6 + 3]; a4 += x * Ws[col * 6 + 4]; a5 += x * Ws[col * 6 + 5];
  }
#pragma unroll
  for (int off = 32; off; off >>= 1) {
    a0 += __shfl_xor(a0, off); a1 += __shfl_xor(a1, off); a2 += __shfl_xor(a2, off);
    a3 += __shfl_xor(a3, off); a4 += __shfl_xor(a4, off); a5 += __shfl_xor(a5, off);
  }
  float r = 0.f;
  if (lane == 0) r = a0; if (lane == 1) r = a1; if (lane == 2) r = a2;
  if (lane == 3) r = a3; if (lane == 4) r = a4; if (lane == 5) r = a5;
  if (lane < 6) out[p * 6 + lane] = r + bc[lane];
}

// ---------------- GEMM v1 (128x128, 4 waves, reg-staged, f32-or-bf16 A): R7-verified ----------------
// ACT: 0 none, 1 relu, 2 sigmoid.
template <int ACT, typename CT, typename AT>
__global__ __launch_bounds__(256)
void k_gemm(const AT* __restrict__ A1, const AT* __restrict__ A2, int ksplit,
            int lda, const bf16_t* __restrict__ Bt, int ldb,
            const float* __restrict__ bias,
            CT* __restrict__ C, int ldc, bf16_t* __restrict__ C2,
            int K, int ntile_n) {
  __shared__ bf16_t As[128][72];
  __shared__ bf16_t Bs[128][72];
  const int tid = threadIdx.x;
  const int wid = tid >> 6;
  const int lane = tid & 63;
  const int wm = wid >> 1, wn = wid & 1;

  const int nwg = gridDim.x;
  const int q = nwg >> 3, rm = nwg & 7;
  const int xcd = blockIdx.x & 7, sub = blockIdx.x >> 3;
  const int wg = ((xcd < rm) ? xcd * (q + 1) : rm * (q + 1) + (xcd - rm) * q) + sub;
  const int mt = wg / ntile_n, nt = wg % ntile_n;
  const long row0 = (long)mt * 128;
  const int col0 = nt * 128;

  f32x4_t acc[4][4];
#pragma unroll
  for (int i = 0; i < 4; ++i)
#pragma unroll
    for (int j = 0; j < 4; ++j) acc[i][j] = (f32x4_t){0.f, 0.f, 0.f, 0.f};

  const int rl = lane & 15;
  const int gsel = lane >> 4;
  const int srow = tid >> 3;
  const int scol = (tid & 7) * 8;

  for (int k0 = 0; k0 < K; k0 += 64) {
    const AT* Ab = (k0 < ksplit) ? (A1 + row0 * lda + k0)
                                 : (A2 + row0 * lda + (k0 - ksplit));
    const bf16_t* Bb = Bt + (long)col0 * ldb + k0;
    __syncthreads();
#pragma unroll
    for (int p = 0; p < 4; ++p) {
      int row = p * 32 + srow;
      bf16x8_t av;
      if constexpr (sizeof(AT) == 4) {
        const f32x4_t* ap = reinterpret_cast<const f32x4_t*>(Ab + (long)row * lda + scol);
        f32x4_t a0 = ap[0], a1 = ap[1];
        av[0] = (bf16_t)a0[0]; av[1] = (bf16_t)a0[1];
        av[2] = (bf16_t)a0[2]; av[3] = (bf16_t)a0[3];
        av[4] = (bf16_t)a1[0]; av[5] = (bf16_t)a1[1];
        av[6] = (bf16_t)a1[2]; av[7] = (bf16_t)a1[3];
      } else {
        av = *reinterpret_cast<const bf16x8_t*>(Ab + (long)row * lda + scol);
      }
      *reinterpret_cast<bf16x8_t*>(&As[row][scol]) = av;
      *reinterpret_cast<bf16x8_t*>(&Bs[row][scol]) =
          *reinterpret_cast<const bf16x8_t*>(Bb + (long)row * ldb + scol);
    }
    __syncthreads();
#pragma unroll
    for (int kk = 0; kk < 64; kk += 32) {
      bf16x8_t af[4], bq[4];
      int kc = kk + gsel * 8;
#pragma unroll
      for (int m = 0; m < 4; ++m)
        af[m] = *reinterpret_cast<const bf16x8_t*>(&As[wm * 64 + m * 16 + rl][kc]);
#pragma unroll
      for (int n = 0; n < 4; ++n)
        bq[n] = *reinterpret_cast<const bf16x8_t*>(&Bs[wn * 64 + n * 16 + rl][kc]);
#pragma unroll
      for (int m = 0; m < 4; ++m)
#pragma unroll
        for (int n = 0; n < 4; ++n)
          acc[m][n] = __builtin_amdgcn_mfma_f32_16x16x32_bf16(af[m], bq[n], acc[m][n], 0, 0, 0);
    }
  }

  const int rg = lane >> 4;
#pragma unroll
  for (int m = 0; m < 4; ++m) {
#pragma unroll
    for (int n = 0; n < 4; ++n) {
      const int col = col0 + wn * 64 + n * 16 + rl;
      const long rowb = row0 + wm * 64 + m * 16 + rg * 4;
      const float bv = bias ? bias[col] : 0.f;
#pragma unroll
      for (int r = 0; r < 4; ++r) {
        const long row = rowb + r;
        float v = acc[m][n][r] + bv;
        if (ACT == 1) v = fmaxf(v, 0.f);
        if (ACT == 2) v = 1.f / (1.f + __expf(-v));
        C[row * (long)ldc + col] = (CT)v;
        if (C2) C2[row * (long)ldc + col] = (bf16_t)v;
      }
    }
  }
}

// ---------------- Fused ni/nh + GRU gate (k_ggate), v1 geometry ----------------
// Tile 128 rows x 128 cols, 4 waves (2x2, each 64x64). Two sequential K=512 phases
// sharing the same LDS buffers (exact v1 staging pattern, 32 MFMAs/K-step):
//   phase 0: ni += agg @ Wihn   (A = Xout cols 0:512)
//   phase 1: nh += x   @ Whhn   (A = Xin cols 512:1024)
// Epilogue: r,z from rz_buf (already sigmoided), x_old from Xin;
//   x_new = (1-z)*tanh(ni+bni + r*(nh+bnh)) + z*x_old -> Xout cols 512:1024.
// tanh via 1 - 2/(e^{2v}+1): one v_exp + rcp, safe at +-inf.
// Ping-pong (Xin != Xout) makes the x read/write race-free.
__global__ __launch_bounds__(256)
void k_ggate(const bf16_t* __restrict__ Agg,    // Xout base (agg at row*1024 + k)
             const bf16_t* __restrict__ Xin512, // Xin + 512 (x at row*1024 + c)
             const bf16_t* __restrict__ Wihn,   // [512][512] N-major
             const bf16_t* __restrict__ Whhn,   // [512][512] N-major
             const float* __restrict__ bni, const float* __restrict__ bnh,
             const bf16_t* __restrict__ rz,     // [N][1024]: sigmoid(r) | sigmoid(z)
             bf16_t* __restrict__ Xout512,      // Xout + 512
             int ntile_n) {
  __shared__ bf16_t As[128][72];
  __shared__ bf16_t Bs[128][72];
  const int tid = threadIdx.x;
  const int wid = tid >> 6;
  const int lane = tid & 63;
  const int wm = wid >> 1, wn = wid & 1;

  const int nwg = gridDim.x;
  const int q = nwg >> 3, rm = nwg & 7;
  const int xcd = blockIdx.x & 7, sub = blockIdx.x >> 3;
  const int wg = ((xcd < rm) ? xcd * (q + 1) : rm * (q + 1) + (xcd - rm) * q) + sub;
  const int mt = wg / ntile_n, nt = wg % ntile_n;
  const long row0 = (long)mt * 128;
  const int col0 = nt * 128;

  f32x4_t ni[4][4], nh[4][4];
#pragma unroll
  for (int i = 0; i < 4; ++i)
#pragma unroll
    for (int j = 0; j < 4; ++j) {
      ni[i][j] = (f32x4_t){0.f, 0.f, 0.f, 0.f};
      nh[i][j] = (f32x4_t){0.f, 0.f, 0.f, 0.f};
    }

  const int rl = lane & 15;
  const int gsel = lane >> 4;
  const int srow = tid >> 3;
  const int scol = (tid & 7) * 8;

  // ---- phase 0: ni = agg @ Wihn ----
  for (int k0 = 0; k0 < 512; k0 += 64) {
    const bf16_t* Ab = Agg + row0 * 1024 + k0;
    const bf16_t* Bb = Wihn + (long)col0 * 512 + k0;
    __syncthreads();
#pragma unroll
    for (int p = 0; p < 4; ++p) {
      int row = p * 32 + srow;
      *reinterpret_cast<bf16x8_t*>(&As[row][scol]) =
          *reinterpret_cast<const bf16x8_t*>(Ab + (long)row * 1024 + scol);
      *reinterpret_cast<bf16x8_t*>(&Bs[row][scol]) =
          *reinterpret_cast<const bf16x8_t*>(Bb + (long)row * 512 + scol);
    }
    __syncthreads();
#pragma unroll
    for (int kk = 0; kk < 64; kk += 32) {
      bf16x8_t af[4], bq[4];
      int kc = kk + gsel * 8;
#pragma unroll
      for (int m = 0; m < 4; ++m)
        af[m] = *reinterpret_cast<const bf16x8_t*>(&As[wm * 64 + m * 16 + rl][kc]);
#pragma unroll
      for (int n = 0; n < 4; ++n)
        bq[n] = *reinterpret_cast<const bf16x8_t*>(&Bs[wn * 64 + n * 16 + rl][kc]);
#pragma unroll
      for (int m = 0; m < 4; ++m)
#pragma unroll
        for (int n = 0; n < 4; ++n)
          ni[m][n] = __builtin_amdgcn_mfma_f32_16x16x32_bf16(af[m], bq[n], ni[m][n], 0, 0, 0);
    }
  }
  // ---- phase 1: nh = x @ Whhn ----
  for (int k0 = 0; k0 < 512; k0 += 64) {
    const bf16_t* Ab = Xin512 + row0 * 1024 + k0;
    const bf16_t* Bb = Whhn + (long)col0 * 512 + k0;
    __syncthreads();
#pragma unroll
    for (int p = 0; p < 4; ++p) {
      int row = p * 32 + srow;
      *reinterpret_cast<bf16x8_t*>(&As[row][scol]) =
          *reinterpret_cast<const bf16x8_t*>(Ab + (long)row * 1024 + scol);
      *reinterpret_cast<bf16x8_t*>(&Bs[row][scol]) =
          *reinterpret_cast<const bf16x8_t*>(Bb + (long)row * 512 + scol);
    }
    __syncthreads();
#pragma unroll
    for (int kk = 0; kk < 64; kk += 32) {
      bf16x8_t af[4], bq[4];
      int kc = kk + gsel * 8;
#pragma unroll
      for (int m = 0; m < 4; ++m)
        af[m] = *reinterpret_cast<const bf16x8_t*>(&As[wm * 64 + m * 16 + rl][kc]);
#pragma unroll
      for (int n = 0; n < 4; ++n)
        bq[n] = *reinterpret_cast<const bf16x8_t*>(&Bs[wn * 64 + n * 16 + rl][kc]);
#pragma unroll
      for (int m = 0; m < 4; ++m)
#pragma unroll
        for (int n = 0; n < 4; ++n)
          nh[m][n] = __builtin_amdgcn_mfma_f32_16x16x32_bf16(af[m], bq[n], nh[m][n], 0, 0, 0);
    }
  }

  // ---- gate epilogue (fast tanh) ----
  const int rg = lane >> 4;
#pragma unroll
  for (int m = 0; m < 4; ++m) {
#pragma unroll
    for (int n = 0; n < 4; ++n) {
      const int col = col0 + wn * 64 + n * 16 + rl;
      const long rowb = row0 + wm * 64 + m * 16 + rg * 4;
      const float bniv = bni[col];
      const float bnhv = bnh[col];
#pragma unroll
      for (int r = 0; r < 4; ++r) {
        const long row = rowb + r;
        const float rr = (float)rz[row * 1024 + col];
        const float zz = (float)rz[row * 1024 + 512 + col];
        const float xv = (float)Xin512[row * 1024 + col];
        const float v = ni[m][n][r] + bniv + rr * (nh[m][n][r] + bnhv);
        const float e2 = __expf(2.f * v);
        const float nn = 1.f - 2.f / (e2 + 1.f);
        Xout512[row * 1024 + col] = (bf16_t)((1.f - zz) * nn + zz * xv);
      }
    }
  }
}

template <typename CT, typename AT>
static void launch_gemm(int act, hipStream_t stream,
                        const AT* A1, const AT* A2, int ksplit, int lda,
                        const bf16_t* Bt, int ldb, const float* bias,
                        CT* C, int ldc, bf16_t* C2, int M, int Nn, int K) {
  int nt = Nn / 128;
  dim3 grid((M / 128) * nt);
  switch (act) {
    case 0: k_gemm<0, CT, AT><<<grid, 256, 0, stream>>>(A1, A2, ksplit, lda, Bt, ldb, bias, C, ldc, C2, K, nt); break;
    case 1: k_gemm<1, CT, AT><<<grid, 256, 0, stream>>>(A1, A2, ksplit, lda, Bt, ldb, bias, C, ldc, C2, K, nt); break;
    case 2: k_gemm<2, CT, AT><<<grid, 256, 0, stream>>>(A1, A2, ksplit, lda, Bt, ldb, bias, C, ldc, C2, K, nt); break;
  }
}

// ---------------- host ----------------

extern "C" void kernel_launch(void* const* d_in, const int* in_sizes, int n_in,
                              void* d_out, int out_size, void* d_ws, size_t ws_size,
                              hipStream_t stream) {
  const float* pair    = (const float*)d_in[0];
  const float* person_a = (const float*)d_in[1];
  const float* person_b = (const float*)d_in[2];
  const float* bbox    = (const float*)d_in[3];
  const int*   rel     = (const int*)d_in[4];
  const int*   edge    = (const int*)d_in[5];
  const float* W_pair  = (const float*)d_in[6];
  const float* b_pair  = (const float*)d_in[7];
  const float* W_pa    = (const float*)d_in[8];
  const float* b_pa    = (const float*)d_in[9];
  const float* W_pb    = (const float*)d_in[10];
  const float* b_pb    = (const float*)d_in[11];
  const float* W_bbox  = (const float*)d_in[12];
  const float* b_bbox  = (const float*)d_in[13];
  const float* W_fcp   = (const float*)d_in[14];
  const float* b_fcp   = (const float*)d_in[15];
  const float* ggc_w   = (const float*)d_in[16];
  const float* gW_ih   = (const float*)d_in[17];
  const float* gW_hh   = (const float*)d_in[18];
  const float* gb_ih   = (const float*)d_in[19];
  const float* gb_hh   = (const float*)d_in[20];
  const float* W_cls   = (const float*)d_in[21];
  const float* b_cls   = (const float*)d_in[22];

  const int Np = in_sizes[0] / 1024;
  const int B  = in_sizes[4];
  const int E  = in_sizes[5] / 2;
  const int N  = Np + B;

  float* out     = (float*)d_out;
  float* out_cls = out;
  float* out_PP  = out_cls + (long)Np * 6;
  float* out_PA  = out_PP + (long)Np * 512;
  float* out_PB  = out_PA + (long)B * 512;
  float* out_HL  = out_PB + (long)B * 512;
  float* out_RF  = out_HL + (long)Np * 512;

  char* w = (char*)d_ws;
  auto alloc = [&](size_t bytes) -> char* {
    char* p = w;
    w += (bytes + 255) & ~(size_t)255;
    return p;
  };
  bf16_t* paP_bf  = (bf16_t*)alloc((size_t)B * 512 * 2);
  bf16_t* pbP_bf  = (bf16_t*)alloc((size_t)B * 512 * 2);
  bf16_t* fcp_bf  = (bf16_t*)alloc((size_t)B * 512 * 2);
  bf16_t* XA      = (bf16_t*)alloc((size_t)N * 1024 * 2);
  bf16_t* XB      = (bf16_t*)alloc((size_t)N * 1024 * 2);
  bf16_t* m_bf    = (bf16_t*)alloc((size_t)N * 512 * 2);
  bf16_t* rz_buf  = (bf16_t*)alloc((size_t)N * 1024 * 2);
  bf16_t* WpairT  = (bf16_t*)alloc((size_t)512 * 1024 * 2);
  bf16_t* WpaT    = (bf16_t*)alloc((size_t)512 * 1024 * 2);
  bf16_t* WpbT    = (bf16_t*)alloc((size_t)512 * 1024 * 2);
  bf16_t* WfcpT   = (bf16_t*)alloc((size_t)512 * 1024 * 2);
  bf16_t* WlT     = (bf16_t*)alloc((size_t)3 * 512 * 512 * 2);
  bf16_t* WgrzT   = (bf16_t*)alloc((size_t)1024 * 1024 * 2);
  bf16_t* WihnT   = (bf16_t*)alloc((size_t)512 * 512 * 2);
  bf16_t* WhhnT   = (bf16_t*)alloc((size_t)512 * 512 * 2);
  float*  b_rz    = (float*)alloc(1024 * 4);
  int* cum      = (int*)alloc((size_t)(B + 1) * 4);
  int* src      = (int*)alloc((size_t)N * 4);
  int* pair_pos = (int*)alloc((size_t)Np * 4);
  int* counts   = (int*)alloc((size_t)N * 4);
  int* row_ptr  = (int*)alloc((size_t)(N + 1) * 4);
  int* cursor   = (int*)alloc((size_t)N * 4);
  int* esrc     = (int*)alloc((size_t)E * 4);
  if ((size_t)(w - (char*)d_ws) > ws_size) return;

  // 1. graph index construction
  k_scan_rel<<<1, 1024, 0, stream>>>(rel, B, cum);
  k_build_src<<<B, 64, 0, stream>>>(cum, B, Np, src, pair_pos);
  // 2. CSR by destination
  k_zero_i32<<<(N + 255) / 256, 256, 0, stream>>>(counts, N);
  k_count<<<(E + 255) / 256, 256, 0, stream>>>(edge + E, E, counts);
  k_scan_counts<<<1, 1024, 0, stream>>>(counts, N, row_ptr, cursor, (N + 1023) / 1024);
  k_scatter<<<(E + 255) / 256, 256, 0, stream>>>(edge, edge + E, E, cursor, esrc);
  // 3. weight transposes (B-operands stored as Bt [N][K])
  dim3 tb(32, 8);
  k_tconv<<<dim3(16, 32), tb, 0, stream>>>(W_pair, 512, 0, 1024, 512, WpairT, 1024, 0);
  k_tconv<<<dim3(16, 32), tb, 0, stream>>>(W_pa, 512, 0, 1024, 512, WpaT, 1024, 0);
  k_tconv<<<dim3(16, 32), tb, 0, stream>>>(W_pb, 512, 0, 1024, 512, WpbT, 1024, 0);
  k_tconv<<<dim3(16, 32), tb, 0, stream>>>(W_fcp, 512, 0, 1024, 512, WfcpT, 1024, 0);
  for (int l = 0; l < 3; ++l)
    k_tconv<<<dim3(16, 16), tb, 0, stream>>>(ggc_w + (long)l * 512 * 512, 512, 0, 512, 512,
                                             WlT + (long)l * 512 * 512, 512, 0);
  k_tconv<<<dim3(32, 16), tb, 0, stream>>>(gW_ih, 1536, 0, 512, 1024, WgrzT, 1024, 0);
  k_tconv<<<dim3(32, 16), tb, 0, stream>>>(gW_hh, 1536, 0, 512, 1024, WgrzT, 1024, 512);
  k_tconv<<<dim3(16, 16), tb, 0, stream>>>(gW_ih, 1536, 1024, 512, 512, WihnT, 512, 0);
  k_tconv<<<dim3(16, 16), tb, 0, stream>>>(gW_hh, 1536, 1024, 512, 512, WhhnT, 512, 0);
  k_brz<<<4, 256, 0, stream>>>(gb_ih, gb_hh, b_rz);
  // 4. projections (f32 A read directly; f32 outputs to d_out; bf16 copies downstream)
  launch_gemm<float, float>(1, stream, person_a, person_a, 1024, 1024, WpaT, 1024, b_pa, out_PA, 512, paP_bf, B, 512, 1024);
  launch_gemm<float, float>(1, stream, person_b, person_b, 1024, 1024, WpbT, 1024, b_pb, out_PB, 512, pbP_bf, B, 512, 1024);
  launch_gemm<float, float>(1, stream, pair, pair, 1024, 1024, WpairT, 1024, b_pair, out_PP, 512, nullptr, Np, 512, 1024);
  launch_gemm<bf16_t, bf16_t>(0, stream, paP_bf, pbP_bf, 512, 512, WfcpT, 1024, b_fcp, fcp_bf, 512, nullptr, B, 512, 1024);
  k_hlevel<<<Np / 2, 256, 0, stream>>>(bbox, W_bbox, b_bbox, out_HL, Np);
  // 5. build node features x into XA cols 512:1024
  k_gather_x<<<((long)N * 64 + 255) / 256, 256, 0, stream>>>(src, out_PP, fcp_bf, Np, N, XA);
  // 6. GatedGraphConv layers (ping-pong XA/XB)
  bf16_t* Xin = XA;
  bf16_t* Xout = XB;
  for (int l = 0; l < 3; ++l) {
    // m = x @ Wl
    launch_gemm<bf16_t, bf16_t>(0, stream, Xin + 512, Xin + 512, 512, 1024,
                                WlT + (long)l * 512 * 512, 512, nullptr, m_bf, 512, nullptr,
                                N, 512, 512);
    // agg -> Xout cols 0:512 (wave per node)
    k_agg<<<(N + 3) / 4, 256, 0, stream>>>(m_bf, row_ptr, esrc, Xout, N);
    // r,z = sigmoid([agg|x] @ Wgrz + b_rz) -> rz_buf  (A split: agg from Xout, x from Xin)
    launch_gemm<bf16_t, bf16_t>(2, stream, Xout, Xin + 512, 512, 1024, WgrzT, 1024,
                                b_rz, rz_buf, 1024, nullptr, N, 1024, 1024);
    // fused ni/nh + gate -> Xout cols 512:1024 (v1 geometry, ntile_n = 4)
    k_ggate<<<(N / 128) * 4, 256, 0, stream>>>(Xout, Xin + 512, WihnT, WhhnT,
                                               gb_ih + 1024, gb_hh + 1024, rz_buf,
                                               Xout + 512, 4);
    bf16_t* tmp = Xin; Xin = Xout; Xout = tmp;
  }
  // final x lives in Xin after the last swap
  k_final<<<((long)Np * 64 + 255) / 256, 256, 0, stream>>>(pair_pos, Xin, out_RF, Np);
  k_cls<<<(Np + 3) / 4, 256, 0, stream>>>(out_RF, W_cls, b_cls, out_cls, Np);
}

// Round 14
// 1206.881 us; speedup vs baseline: 1.0397x; 1.0397x over previous
//
#include <hip/hip_runtime.h>
#include <hip/hip_bf16.h>
#include <stdint.h>

typedef __bf16 bf16_t;
typedef __bf16 bf16x8_t __attribute__((ext_vector_type(8)));
typedef __bf16 bf16x4_t __attribute__((ext_vector_type(4)));
typedef float  f32x4_t  __attribute__((ext_vector_type(4)));

// ---------------- setup / elementwise kernels ----------------

// dst[c][dst_col0 + k] = src[k][src_col0 + c], k<R, c<C  (transpose + f32->bf16)
__global__ void k_tconv(const float* __restrict__ src, int src_ld, int src_col0, int R, int C,
                        bf16_t* __restrict__ dst, int dst_ld, int dst_col0) {
  __shared__ float t[32][33];
  int c0 = blockIdx.x * 32, k0 = blockIdx.y * 32;
  int tx = threadIdx.x, ty = threadIdx.y;
#pragma unroll
  for (int j = 0; j < 32; j += 8) {
    int k = k0 + ty + j, c = c0 + tx;
    t[ty + j][tx] = src[(long)k * src_ld + src_col0 + c];
  }
  __syncthreads();
#pragma unroll
  for (int j = 0; j < 32; j += 8) {
    int c = c0 + ty + j, k = k0 + tx;
    dst[(long)c * dst_ld + dst_col0 + k] = (bf16_t)t[tx][ty + j];
  }
}

__global__ void k_brz(const float* __restrict__ bih, const float* __restrict__ bhh,
                      float* __restrict__ brz) {
  int c = blockIdx.x * 256 + threadIdx.x;
  if (c < 1024) brz[c] = bih[c] + bhh[c];
}

__global__ void k_scan_rel(const int* __restrict__ rel, int B, int* __restrict__ cum) {
  __shared__ int s[1024];
  int t = threadIdx.x;
  s[t] = (t < B) ? rel[t] : 0;
  __syncthreads();
  for (int off = 1; off < 1024; off <<= 1) {
    int v = (t >= off) ? s[t - off] : 0;
    __syncthreads();
    s[t] += v;
    __syncthreads();
  }
  if (t == 0) cum[0] = 0;
  cum[t + 1] = s[t];
}

__global__ void k_build_src(const int* __restrict__ cum, int B, int Np,
                            int* __restrict__ src, int* __restrict__ pair_pos) {
  int i = blockIdx.x, t = threadIdx.x;
  int c = cum[i], c1 = cum[i + 1];
  int r = c1 - c;
  if (t < r) { int g = c + i + t; src[g] = c + t; pair_pos[c + t] = g; }
  if (t == r) src[c1 + i] = Np + i;
}

__global__ void k_zero_i32(int* __restrict__ p, int n) {
  int i = blockIdx.x * 256 + threadIdx.x;
  if (i < n) p[i] = 0;
}

__global__ void k_count(const int* __restrict__ dvec, int E, int* __restrict__ counts) {
  int e = blockIdx.x * 256 + threadIdx.x;
  if (e < E) atomicAdd(&counts[dvec[e]], 1);
}

__global__ void k_scan_counts(const int* __restrict__ counts, int N,
                              int* __restrict__ row_ptr, int* __restrict__ cursor, int CH) {
  __shared__ int s[1024];
  int t = threadIdx.x;
  int base = t * CH;
  int tot = 0;
  for (int j = 0; j < CH; ++j) { int idx = base + j; if (idx < N) tot += counts[idx]; }
  s[t] = tot;
  __syncthreads();
  for (int off = 1; off < 1024; off <<= 1) {
    int v = (t >= off) ? s[t - off] : 0;
    __syncthreads();
    s[t] += v;
    __syncthreads();
  }
  int excl = s[t] - tot;
  int run = excl;
  for (int j = 0; j < CH; ++j) {
    int idx = base + j;
    if (idx < N) { row_ptr[idx] = run; cursor[idx] = run; run += counts[idx]; }
  }
  if (t == 1023) row_ptr[N] = s[1023];
}

__global__ void k_scatter(const int* __restrict__ svec, const int* __restrict__ dvec, int E,
                          int* __restrict__ cursor, int* __restrict__ esrc) {
  int e = blockIdx.x * 256 + threadIdx.x;
  if (e < E) { int pos = atomicAdd(&cursor[dvec[e]], 1); esrc[pos] = svec[e]; }
}

// Build x (cols 512:1024 of XA). Pair rows from f32 personPair output; person rows from fc_person.
__global__ void k_gather_x(const int* __restrict__ src, const float* __restrict__ PPf,
                           const bf16_t* __restrict__ FCP, int Np, int N,
                           bf16_t* __restrict__ Xcat) {
  long idx = (long)blockIdx.x * 256 + threadIdx.x;
  long g = idx >> 6;
  int t = idx & 63;
  if (g >= N) return;
  int s = src[g];
  bf16x8_t o;
  if (s < Np) {
    const f32x4_t* r4 = reinterpret_cast<const f32x4_t*>(PPf + (long)s * 512);
    f32x4_t a = r4[2 * t], b = r4[2 * t + 1];
    o[0] = (bf16_t)a[0]; o[1] = (bf16_t)a[1]; o[2] = (bf16_t)a[2]; o[3] = (bf16_t)a[3];
    o[4] = (bf16_t)b[0]; o[5] = (bf16_t)b[1]; o[6] = (bf16_t)b[2]; o[7] = (bf16_t)b[3];
  } else {
    o = reinterpret_cast<const bf16x8_t*>(FCP + (long)(s - Np) * 512)[t];
  }
  reinterpret_cast<bf16x8_t*>(Xcat + g * 1024 + 512)[t] = o;
}

// agg[v] = sum over incoming edges of m[src_e]; written as bf16 into Xout cols 0:512
__global__ void k_agg(const bf16_t* __restrict__ m, const int* __restrict__ row_ptr,
                      const int* __restrict__ esrc, bf16_t* __restrict__ Xout) {
  int v = blockIdx.x;
  int t = threadIdx.x;  // 128 threads x 4 cols
  int beg = row_ptr[v], end = row_ptr[v + 1];
  float a0 = 0.f, a1 = 0.f, a2 = 0.f, a3 = 0.f;
  for (int e = beg; e < end; ++e) {
    int s = esrc[e];
    bf16x4_t mv = reinterpret_cast<const bf16x4_t*>(m + (long)s * 512)[t];
    a0 += (float)mv[0]; a1 += (float)mv[1]; a2 += (float)mv[2]; a3 += (float)mv[3];
  }
  bf16x4_t o;
  o[0] = (bf16_t)a0; o[1] = (bf16_t)a1; o[2] = (bf16_t)a2; o[3] = (bf16_t)a3;
  reinterpret_cast<bf16x4_t*>(Xout + (long)v * 1024)[t] = o;
}

// hLevelF = relu(bbox @ W_bbox + b_bbox), K=8 -> f32 output
__global__ void k_hlevel(const float* __restrict__ bbox, const float* __restrict__ W,
                         const float* __restrict__ b, float* __restrict__ out, int Np) {
  __shared__ float Ws[8][512];
  __shared__ float bs[512];
  int t = threadIdx.x;
  for (int i = t; i < 8 * 512; i += 256) Ws[i >> 9][i & 511] = W[i];
  for (int i = t; i < 512; i += 256) bs[i] = b[i];
  __syncthreads();
  long idx = (long)blockIdx.x * 256 + t;
  long p = idx >> 7;
  int c4 = (int)(idx & 127) * 4;
  if (p >= Np) return;
  f32x4_t bb0 = reinterpret_cast<const f32x4_t*>(bbox + p * 8)[0];
  f32x4_t bb1 = reinterpret_cast<const f32x4_t*>(bbox + p * 8)[1];
  float acc0 = bs[c4], acc1 = bs[c4 + 1], acc2 = bs[c4 + 2], acc3 = bs[c4 + 3];
#pragma unroll
  for (int i = 0; i < 4; ++i) {
    acc0 += bb0[i] * Ws[i][c4];     acc1 += bb0[i] * Ws[i][c4 + 1];
    acc2 += bb0[i] * Ws[i][c4 + 2]; acc3 += bb0[i] * Ws[i][c4 + 3];
    acc0 += bb1[i] * Ws[4 + i][c4];     acc1 += bb1[i] * Ws[4 + i][c4 + 1];
    acc2 += bb1[i] * Ws[4 + i][c4 + 2]; acc3 += bb1[i] * Ws[4 + i][c4 + 3];
  }
  f32x4_t o;
  o[0] = fmaxf(acc0, 0.f); o[1] = fmaxf(acc1, 0.f);
  o[2] = fmaxf(acc2, 0.f); o[3] = fmaxf(acc3, 0.f);
  reinterpret_cast<f32x4_t*>(out + p * 512)[idx & 127] = o;
}

__global__ void k_final(const int* __restrict__ pair_pos, const bf16_t* __restrict__ Xcat,
                        float* __restrict__ outRF, int Np) {
  long idx = (long)blockIdx.x * 256 + threadIdx.x;
  long p = idx >> 6;
  int t = idx & 63;
  if (p >= Np) return;
  int g = pair_pos[p];
  bf16x8_t x = reinterpret_cast<const bf16x8_t*>(Xcat + (long)g * 1024 + 512)[t];
  f32x4_t o0, o1;
#pragma unroll
  for (int j = 0; j < 4; ++j) {
    o0[j] = 1.f / (1.f + __expf(-(float)x[j]));
    o1[j] = 1.f / (1.f + __expf(-(float)x[4 + j]));
  }
  f32x4_t* dst = reinterpret_cast<f32x4_t*>(outRF + p * 512);
  dst[2 * t] = o0;
  dst[2 * t + 1] = o1;
}

// fc_pairClass = RF @ W_cls + b_cls  (K=512, N=6): one wave per row, f32 in/out
__global__ void k_cls(const float* __restrict__ RF, const float* __restrict__ Wc,
                      const float* __restrict__ bc, float* __restrict__ out, int Np) {
  __shared__ float Ws[512 * 6];
  int t = threadIdx.x;
  for (int i = t; i < 512 * 6; i += 256) Ws[i] = Wc[i];
  __syncthreads();
  int wid = t >> 6, lane = t & 63;
  long p = (long)blockIdx.x * 4 + wid;
  if (p >= Np) return;
  const f32x4_t* r4 = reinterpret_cast<const f32x4_t*>(RF + p * 512);
  f32x4_t v0 = r4[2 * lane], v1 = r4[2 * lane + 1];
  float a0 = 0, a1 = 0, a2 = 0, a3 = 0, a4 = 0, a5 = 0;
#pragma unroll
  for (int jj = 0; jj < 8; ++jj) {
    float x = (jj < 4) ? v0[jj] : v1[jj - 4];
    int col = lane * 8 + jj;
    a0 += x * Ws[col * 6 + 0]; a1 += x * Ws[col * 6 + 1]; a2 += x * Ws[col * 6 + 2];
    a3 += x * Ws[col * 6 + 3]; a4 += x * Ws[col * 6 + 4]; a5 += x * Ws[col * 6 + 5];
  }
#pragma unroll
  for (int off = 32; off; off >>= 1) {
    a0 += __shfl_xor(a0, off); a1 += __shfl_xor(a1, off); a2 += __shfl_xor(a2, off);
    a3 += __shfl_xor(a3, off); a4 += __shfl_xor(a4, off); a5 += __shfl_xor(a5, off);
  }
  float r = 0.f;
  if (lane == 0) r = a0; if (lane == 1) r = a1; if (lane == 2) r = a2;
  if (lane == 3) r = a3; if (lane == 4) r = a4; if (lane == 5) r = a5;
  if (lane < 6) out[p * 6 + lane] = r + bc[lane];
}

// ---------------- GEMM v1 (128x128, 4 waves, reg-staged, f32-or-bf16 A): R7-verified ----------------
// ACT: 0 none, 1 relu, 2 sigmoid.
template <int ACT, typename CT, typename AT>
__global__ __launch_bounds__(256)
void k_gemm(const AT* __restrict__ A1, const AT* __restrict__ A2, int ksplit,
            int lda, const bf16_t* __restrict__ Bt, int ldb,
            const float* __restrict__ bias,
            CT* __restrict__ C, int ldc, bf16_t* __restrict__ C2,
            int K, int ntile_n) {
  __shared__ bf16_t As[128][72];
  __shared__ bf16_t Bs[128][72];
  const int tid = threadIdx.x;
  const int wid = tid >> 6;
  const int lane = tid & 63;
  const int wm = wid >> 1, wn = wid & 1;

  const int nwg = gridDim.x;
  const int q = nwg >> 3, rm = nwg & 7;
  const int xcd = blockIdx.x & 7, sub = blockIdx.x >> 3;
  const int wg = ((xcd < rm) ? xcd * (q + 1) : rm * (q + 1) + (xcd - rm) * q) + sub;
  const int mt = wg / ntile_n, nt = wg % ntile_n;
  const long row0 = (long)mt * 128;
  const int col0 = nt * 128;

  f32x4_t acc[4][4];
#pragma unroll
  for (int i = 0; i < 4; ++i)
#pragma unroll
    for (int j = 0; j < 4; ++j) acc[i][j] = (f32x4_t){0.f, 0.f, 0.f, 0.f};

  const int rl = lane & 15;
  const int gsel = lane >> 4;
  const int srow = tid >> 3;
  const int scol = (tid & 7) * 8;

  for (int k0 = 0; k0 < K; k0 += 64) {
    const AT* Ab = (k0 < ksplit) ? (A1 + row0 * lda + k0)
                                 : (A2 + row0 * lda + (k0 - ksplit));
    const bf16_t* Bb = Bt + (long)col0 * ldb + k0;
    __syncthreads();
#pragma unroll
    for (int p = 0; p < 4; ++p) {
      int row = p * 32 + srow;
      bf16x8_t av;
      if constexpr (sizeof(AT) == 4) {
        const f32x4_t* ap = reinterpret_cast<const f32x4_t*>(Ab + (long)row * lda + scol);
        f32x4_t a0 = ap[0], a1 = ap[1];
        av[0] = (bf16_t)a0[0]; av[1] = (bf16_t)a0[1];
        av[2] = (bf16_t)a0[2]; av[3] = (bf16_t)a0[3];
        av[4] = (bf16_t)a1[0]; av[5] = (bf16_t)a1[1];
        av[6] = (bf16_t)a1[2]; av[7] = (bf16_t)a1[3];
      } else {
        av = *reinterpret_cast<const bf16x8_t*>(Ab + (long)row * lda + scol);
      }
      *reinterpret_cast<bf16x8_t*>(&As[row][scol]) = av;
      *reinterpret_cast<bf16x8_t*>(&Bs[row][scol]) =
          *reinterpret_cast<const bf16x8_t*>(Bb + (long)row * ldb + scol);
    }
    __syncthreads();
#pragma unroll
    for (int kk = 0; kk < 64; kk += 32) {
      bf16x8_t af[4], bq[4];
      int kc = kk + gsel * 8;
#pragma unroll
      for (int m = 0; m < 4; ++m)
        af[m] = *reinterpret_cast<const bf16x8_t*>(&As[wm * 64 + m * 16 + rl][kc]);
#pragma unroll
      for (int n = 0; n < 4; ++n)
        bq[n] = *reinterpret_cast<const bf16x8_t*>(&Bs[wn * 64 + n * 16 + rl][kc]);
#pragma unroll
      for (int m = 0; m < 4; ++m)
#pragma unroll
        for (int n = 0; n < 4; ++n)
          acc[m][n] = __builtin_amdgcn_mfma_f32_16x16x32_bf16(af[m], bq[n], acc[m][n], 0, 0, 0);
    }
  }

  const int rg = lane >> 4;
#pragma unroll
  for (int m = 0; m < 4; ++m) {
#pragma unroll
    for (int n = 0; n < 4; ++n) {
      const int col = col0 + wn * 64 + n * 16 + rl;
      const long rowb = row0 + wm * 64 + m * 16 + rg * 4;
      const float bv = bias ? bias[col] : 0.f;
#pragma unroll
      for (int r = 0; r < 4; ++r) {
        const long row = rowb + r;
        float v = acc[m][n][r] + bv;
        if (ACT == 1) v = fmaxf(v, 0.f);
        if (ACT == 2) v = 1.f / (1.f + __expf(-v));
        C[row * (long)ldc + col] = (CT)v;
        if (C2) C2[row * (long)ldc + col] = (bf16_t)v;
      }
    }
  }
}

// ---------------- Fused ni/nh + GRU gate (k_ggate), v1 geometry ----------------
// Tile 128 rows x 128 cols, 4 waves (2x2, each 64x64). Two sequential K=512 phases
// sharing the same LDS buffers (exact v1 staging pattern, 32 MFMAs/K-step):
//   phase 0: ni += agg @ Wihn   (A = Xout cols 0:512)
//   phase 1: nh += x   @ Whhn   (A = Xin cols 512:1024)
// Epilogue: r,z from rz_buf (already sigmoided), x_old from Xin;
//   x_new = (1-z)*tanh(ni+bni + r*(nh+bnh)) + z*x_old -> Xout cols 512:1024.
// Ping-pong (Xin != Xout) makes the x read/write race-free.
__global__ __launch_bounds__(256)
void k_ggate(const bf16_t* __restrict__ Agg,    // Xout base (agg at row*1024 + k)
             const bf16_t* __restrict__ Xin512, // Xin + 512 (x at row*1024 + c)
             const bf16_t* __restrict__ Wihn,   // [512][512] N-major
             const bf16_t* __restrict__ Whhn,   // [512][512] N-major
             const float* __restrict__ bni, const float* __restrict__ bnh,
             const bf16_t* __restrict__ rz,     // [N][1024]: sigmoid(r) | sigmoid(z)
             bf16_t* __restrict__ Xout512,      // Xout + 512
             int ntile_n) {
  __shared__ bf16_t As[128][72];
  __shared__ bf16_t Bs[128][72];
  const int tid = threadIdx.x;
  const int wid = tid >> 6;
  const int lane = tid & 63;
  const int wm = wid >> 1, wn = wid & 1;

  const int nwg = gridDim.x;
  const int q = nwg >> 3, rm = nwg & 7;
  const int xcd = blockIdx.x & 7, sub = blockIdx.x >> 3;
  const int wg = ((xcd < rm) ? xcd * (q + 1) : rm * (q + 1) + (xcd - rm) * q) + sub;
  const int mt = wg / ntile_n, nt = wg % ntile_n;
  const long row0 = (long)mt * 128;
  const int col0 = nt * 128;

  f32x4_t ni[4][4], nh[4][4];
#pragma unroll
  for (int i = 0; i < 4; ++i)
#pragma unroll
    for (int j = 0; j < 4; ++j) {
      ni[i][j] = (f32x4_t){0.f, 0.f, 0.f, 0.f};
      nh[i][j] = (f32x4_t){0.f, 0.f, 0.f, 0.f};
    }

  const int rl = lane & 15;
  const int gsel = lane >> 4;
  const int srow = tid >> 3;
  const int scol = (tid & 7) * 8;

  // ---- phase 0: ni = agg @ Wihn ----
  for (int k0 = 0; k0 < 512; k0 += 64) {
    const bf16_t* Ab = Agg + row0 * 1024 + k0;
    const bf16_t* Bb = Wihn + (long)col0 * 512 + k0;
    __syncthreads();
#pragma unroll
    for (int p = 0; p < 4; ++p) {
      int row = p * 32 + srow;
      *reinterpret_cast<bf16x8_t*>(&As[row][scol]) =
          *reinterpret_cast<const bf16x8_t*>(Ab + (long)row * 1024 + scol);
      *reinterpret_cast<bf16x8_t*>(&Bs[row][scol]) =
          *reinterpret_cast<const bf16x8_t*>(Bb + (long)row * 512 + scol);
    }
    __syncthreads();
#pragma unroll
    for (int kk = 0; kk < 64; kk += 32) {
      bf16x8_t af[4], bq[4];
      int kc = kk + gsel * 8;
#pragma unroll
      for (int m = 0; m < 4; ++m)
        af[m] = *reinterpret_cast<const bf16x8_t*>(&As[wm * 64 + m * 16 + rl][kc]);
#pragma unroll
      for (int n = 0; n < 4; ++n)
        bq[n] = *reinterpret_cast<const bf16x8_t*>(&Bs[wn * 64 + n * 16 + rl][kc]);
#pragma unroll
      for (int m = 0; m < 4; ++m)
#pragma unroll
        for (int n = 0; n < 4; ++n)
          ni[m][n] = __builtin_amdgcn_mfma_f32_16x16x32_bf16(af[m], bq[n], ni[m][n], 0, 0, 0);
    }
  }
  // ---- phase 1: nh = x @ Whhn ----
  for (int k0 = 0; k0 < 512; k0 += 64) {
    const bf16_t* Ab = Xin512 + row0 * 1024 + k0;
    const bf16_t* Bb = Whhn + (long)col0 * 512 + k0;
    __syncthreads();
#pragma unroll
    for (int p = 0; p < 4; ++p) {
      int row = p * 32 + srow;
      *reinterpret_cast<bf16x8_t*>(&As[row][scol]) =
          *reinterpret_cast<const bf16x8_t*>(Ab + (long)row * 1024 + scol);
      *reinterpret_cast<bf16x8_t*>(&Bs[row][scol]) =
          *reinterpret_cast<const bf16x8_t*>(Bb + (long)row * 512 + scol);
    }
    __syncthreads();
#pragma unroll
    for (int kk = 0; kk < 64; kk += 32) {
      bf16x8_t af[4], bq[4];
      int kc = kk + gsel * 8;
#pragma unroll
      for (int m = 0; m < 4; ++m)
        af[m] = *reinterpret_cast<const bf16x8_t*>(&As[wm * 64 + m * 16 + rl][kc]);
#pragma unroll
      for (int n = 0; n < 4; ++n)
        bq[n] = *reinterpret_cast<const bf16x8_t*>(&Bs[wn * 64 + n * 16 + rl][kc]);
#pragma unroll
      for (int m = 0; m < 4; ++m)
#pragma unroll
        for (int n = 0; n < 4; ++n)
          nh[m][n] = __builtin_amdgcn_mfma_f32_16x16x32_bf16(af[m], bq[n], nh[m][n], 0, 0, 0);
    }
  }

  // ---- gate epilogue ----
  const int rg = lane >> 4;
#pragma unroll
  for (int m = 0; m < 4; ++m) {
#pragma unroll
    for (int n = 0; n < 4; ++n) {
      const int col = col0 + wn * 64 + n * 16 + rl;
      const long rowb = row0 + wm * 64 + m * 16 + rg * 4;
      const float bniv = bni[col];
      const float bnhv = bnh[col];
#pragma unroll
      for (int r = 0; r < 4; ++r) {
        const long row = rowb + r;
        const float rr = (float)rz[row * 1024 + col];
        const float zz = (float)rz[row * 1024 + 512 + col];
        const float xv = (float)Xin512[row * 1024 + col];
        const float nn = tanhf(ni[m][n][r] + bniv + rr * (nh[m][n][r] + bnhv));
        Xout512[row * 1024 + col] = (bf16_t)((1.f - zz) * nn + zz * xv);
      }
    }
  }
}

template <typename CT, typename AT>
static void launch_gemm(int act, hipStream_t stream,
                        const AT* A1, const AT* A2, int ksplit, int lda,
                        const bf16_t* Bt, int ldb, const float* bias,
                        CT* C, int ldc, bf16_t* C2, int M, int Nn, int K) {
  int nt = Nn / 128;
  dim3 grid((M / 128) * nt);
  switch (act) {
    case 0: k_gemm<0, CT, AT><<<grid, 256, 0, stream>>>(A1, A2, ksplit, lda, Bt, ldb, bias, C, ldc, C2, K, nt); break;
    case 1: k_gemm<1, CT, AT><<<grid, 256, 0, stream>>>(A1, A2, ksplit, lda, Bt, ldb, bias, C, ldc, C2, K, nt); break;
    case 2: k_gemm<2, CT, AT><<<grid, 256, 0, stream>>>(A1, A2, ksplit, lda, Bt, ldb, bias, C, ldc, C2, K, nt); break;
  }
}

// ---------------- host ----------------

extern "C" void kernel_launch(void* const* d_in, const int* in_sizes, int n_in,
                              void* d_out, int out_size, void* d_ws, size_t ws_size,
                              hipStream_t stream) {
  const float* pair    = (const float*)d_in[0];
  const float* person_a = (const float*)d_in[1];
  const float* person_b = (const float*)d_in[2];
  const float* bbox    = (const float*)d_in[3];
  const int*   rel     = (const int*)d_in[4];
  const int*   edge    = (const int*)d_in[5];
  const float* W_pair  = (const float*)d_in[6];
  const float* b_pair  = (const float*)d_in[7];
  const float* W_pa    = (const float*)d_in[8];
  const float* b_pa    = (const float*)d_in[9];
  const float* W_pb    = (const float*)d_in[10];
  const float* b_pb    = (const float*)d_in[11];
  const float* W_bbox  = (const float*)d_in[12];
  const float* b_bbox  = (const float*)d_in[13];
  const float* W_fcp   = (const float*)d_in[14];
  const float* b_fcp   = (const float*)d_in[15];
  const float* ggc_w   = (const float*)d_in[16];
  const float* gW_ih   = (const float*)d_in[17];
  const float* gW_hh   = (const float*)d_in[18];
  const float* gb_ih   = (const float*)d_in[19];
  const float* gb_hh   = (const float*)d_in[20];
  const float* W_cls   = (const float*)d_in[21];
  const float* b_cls   = (const float*)d_in[22];

  const int Np = in_sizes[0] / 1024;
  const int B  = in_sizes[4];
  const int E  = in_sizes[5] / 2;
  const int N  = Np + B;

  float* out     = (float*)d_out;
  float* out_cls = out;
  float* out_PP  = out_cls + (long)Np * 6;
  float* out_PA  = out_PP + (long)Np * 512;
  float* out_PB  = out_PA + (long)B * 512;
  float* out_HL  = out_PB + (long)B * 512;
  float* out_RF  = out_HL + (long)Np * 512;

  char* w = (char*)d_ws;
  auto alloc = [&](size_t bytes) -> char* {
    char* p = w;
    w += (bytes + 255) & ~(size_t)255;
    return p;
  };
  bf16_t* paP_bf  = (bf16_t*)alloc((size_t)B * 512 * 2);
  bf16_t* pbP_bf  = (bf16_t*)alloc((size_t)B * 512 * 2);
  bf16_t* fcp_bf  = (bf16_t*)alloc((size_t)B * 512 * 2);
  bf16_t* XA      = (bf16_t*)alloc((size_t)N * 1024 * 2);
  bf16_t* XB      = (bf16_t*)alloc((size_t)N * 1024 * 2);
  bf16_t* m_bf    = (bf16_t*)alloc((size_t)N * 512 * 2);
  bf16_t* rz_buf  = (bf16_t*)alloc((size_t)N * 1024 * 2);
  bf16_t* WpairT  = (bf16_t*)alloc((size_t)512 * 1024 * 2);
  bf16_t* WpaT    = (bf16_t*)alloc((size_t)512 * 1024 * 2);
  bf16_t* WpbT    = (bf16_t*)alloc((size_t)512 * 1024 * 2);
  bf16_t* WfcpT   = (bf16_t*)alloc((size_t)512 * 1024 * 2);
  bf16_t* WlT     = (bf16_t*)alloc((size_t)3 * 512 * 512 * 2);
  bf16_t* WgrzT   = (bf16_t*)alloc((size_t)1024 * 1024 * 2);
  bf16_t* WihnT   = (bf16_t*)alloc((size_t)512 * 512 * 2);
  bf16_t* WhhnT   = (bf16_t*)alloc((size_t)512 * 512 * 2);
  float*  b_rz    = (float*)alloc(1024 * 4);
  int* cum      = (int*)alloc((size_t)(B + 1) * 4);
  int* src      = (int*)alloc((size_t)N * 4);
  int* pair_pos = (int*)alloc((size_t)Np * 4);
  int* counts   = (int*)alloc((size_t)N * 4);
  int* row_ptr  = (int*)alloc((size_t)(N + 1) * 4);
  int* cursor   = (int*)alloc((size_t)N * 4);
  int* esrc     = (int*)alloc((size_t)E * 4);
  if ((size_t)(w - (char*)d_ws) > ws_size) return;

  // 1. graph index construction
  k_scan_rel<<<1, 1024, 0, stream>>>(rel, B, cum);
  k_build_src<<<B, 64, 0, stream>>>(cum, B, Np, src, pair_pos);
  // 2. CSR by destination
  k_zero_i32<<<(N + 255) / 256, 256, 0, stream>>>(counts, N);
  k_count<<<(E + 255) / 256, 256, 0, stream>>>(edge + E, E, counts);
  k_scan_counts<<<1, 1024, 0, stream>>>(counts, N, row_ptr, cursor, (N + 1023) / 1024);
  k_scatter<<<(E + 255) / 256, 256, 0, stream>>>(edge, edge + E, E, cursor, esrc);
  // 3. weight transposes (B-operands stored as Bt [N][K])
  dim3 tb(32, 8);
  k_tconv<<<dim3(16, 32), tb, 0, stream>>>(W_pair, 512, 0, 1024, 512, WpairT, 1024, 0);
  k_tconv<<<dim3(16, 32), tb, 0, stream>>>(W_pa, 512, 0, 1024, 512, WpaT, 1024, 0);
  k_tconv<<<dim3(16, 32), tb, 0, stream>>>(W_pb, 512, 0, 1024, 512, WpbT, 1024, 0);
  k_tconv<<<dim3(16, 32), tb, 0, stream>>>(W_fcp, 512, 0, 1024, 512, WfcpT, 1024, 0);
  for (int l = 0; l < 3; ++l)
    k_tconv<<<dim3(16, 16), tb, 0, stream>>>(ggc_w + (long)l * 512 * 512, 512, 0, 512, 512,
                                             WlT + (long)l * 512 * 512, 512, 0);
  k_tconv<<<dim3(32, 16), tb, 0, stream>>>(gW_ih, 1536, 0, 512, 1024, WgrzT, 1024, 0);
  k_tconv<<<dim3(32, 16), tb, 0, stream>>>(gW_hh, 1536, 0, 512, 1024, WgrzT, 1024, 512);
  k_tconv<<<dim3(16, 16), tb, 0, stream>>>(gW_ih, 1536, 1024, 512, 512, WihnT, 512, 0);
  k_tconv<<<dim3(16, 16), tb, 0, stream>>>(gW_hh, 1536, 1024, 512, 512, WhhnT, 512, 0);
  k_brz<<<4, 256, 0, stream>>>(gb_ih, gb_hh, b_rz);
  // 4. projections (f32 A read directly; f32 outputs to d_out; bf16 copies downstream)
  launch_gemm<float, float>(1, stream, person_a, person_a, 1024, 1024, WpaT, 1024, b_pa, out_PA, 512, paP_bf, B, 512, 1024);
  launch_gemm<float, float>(1, stream, person_b, person_b, 1024, 1024, WpbT, 1024, b_pb, out_PB, 512, pbP_bf, B, 512, 1024);
  launch_gemm<float, float>(1, stream, pair, pair, 1024, 1024, WpairT, 1024, b_pair, out_PP, 512, nullptr, Np, 512, 1024);
  launch_gemm<bf16_t, bf16_t>(0, stream, paP_bf, pbP_bf, 512, 512, WfcpT, 1024, b_fcp, fcp_bf, 512, nullptr, B, 512, 1024);
  k_hlevel<<<Np / 2, 256, 0, stream>>>(bbox, W_bbox, b_bbox, out_HL, Np);
  // 5. build node features x into XA cols 512:1024
  k_gather_x<<<((long)N * 64 + 255) / 256, 256, 0, stream>>>(src, out_PP, fcp_bf, Np, N, XA);
  // 6. GatedGraphConv layers (ping-pong XA/XB)
  bf16_t* Xin = XA;
  bf16_t* Xout = XB;
  for (int l = 0; l < 3; ++l) {
    // m = x @ Wl
    launch_gemm<bf16_t, bf16_t>(0, stream, Xin + 512, Xin + 512, 512, 1024,
                                WlT + (long)l * 512 * 512, 512, nullptr, m_bf, 512, nullptr,
                                N, 512, 512);
    // agg -> Xout cols 0:512
    k_agg<<<N, 128, 0, stream>>>(m_bf, row_ptr, esrc, Xout);
    // r,z = sigmoid([agg|x] @ Wgrz + b_rz) -> rz_buf  (A split: agg from Xout, x from Xin)
    launch_gemm<bf16_t, bf16_t>(2, stream, Xout, Xin + 512, 512, 1024, WgrzT, 1024,
                                b_rz, rz_buf, 1024, nullptr, N, 1024, 1024);
    // fused ni/nh + gate -> Xout cols 512:1024 (v1 geometry, ntile_n = 4)
    k_ggate<<<(N / 128) * 4, 256, 0, stream>>>(Xout, Xin + 512, WihnT, WhhnT,
                                               gb_ih + 1024, gb_hh + 1024, rz_buf,
                                               Xout + 512, 4);
    bf16_t* tmp = Xin; Xin = Xout; Xout = tmp;
  }
  // final x lives in Xin after the last swap
  k_final<<<((long)Np * 64 + 255) / 256, 256, 0, stream>>>(pair_pos, Xin, out_RF, Np);
  k_cls<<<(Np + 3) / 4, 256, 0, stream>>>(out_RF, W_cls, b_cls, out_cls, Np);
}